// Round 6
// baseline (125.598 us; speedup 1.0000x reference)
//
#include <hip/hip_runtime.h>
#include <hip/hip_bf16.h>

// L=4096, B=16, C_IN=512, C_OUT=512, C_COND=512, K=4, HID=128, T=30
typedef __bf16 bfx8 __attribute__((ext_vector_type(8)));
typedef float f32x4 __attribute__((ext_vector_type(4)));
typedef unsigned short u16x8 __attribute__((ext_vector_type(8)));
typedef unsigned short u16x4 __attribute__((ext_vector_type(4)));

__device__ __forceinline__ unsigned short f2bf(float f) {
    unsigned int u = __builtin_bit_cast(unsigned int, f);
    u += 0x7fffu + ((u >> 16) & 1u);          // RNE
    return (unsigned short)(u >> 16);
}

// XOR swizzle within each 2-row (128 B) unit of a [rows][32] bf16 tile.
// chunk = 16B (8 bf16) slot index within the row. Returns ushort index.
__device__ __forceinline__ int swz_idx(int row, int chunk) {
    const int p = row >> 1;
    const int q = (((row & 1) << 2) | chunk) ^ (p & 7);
    return p * 64 + q * 8;
}

// ---------- kernel 1: conditioning MLP. One block per b. ----------
__global__ __launch_bounds__(1024) void att_kernel(
    const float* __restrict__ cond, const float* __restrict__ fc1w,
    const float* __restrict__ fc1b, const float* __restrict__ fc2w,
    const float* __restrict__ fc2b, const float* __restrict__ bias,
    float* __restrict__ att_out, float* __restrict__ bagg_out)
{
    __shared__ float h[128];
    __shared__ float att_s[4];
    const int b    = blockIdx.x;
    const int tid  = threadIdx.x;
    const int lane = tid & 63;
    const int wv   = tid >> 6;          // 0..15

    for (int j = wv; j < 128; j += 16) {
        const float* c = cond + b * 512 + lane * 8;
        const float* w = fc1w + j * 512 + lane * 8;
        const float4 c0 = *(const float4*)c, c1 = *(const float4*)(c + 4);
        const float4 w0 = *(const float4*)w, w1 = *(const float4*)(w + 4);
        float s = c0.x * w0.x + c0.y * w0.y + c0.z * w0.z + c0.w * w0.w
                + c1.x * w1.x + c1.y * w1.y + c1.z * w1.z + c1.w * w1.w;
        #pragma unroll
        for (int off = 32; off; off >>= 1) s += __shfl_down(s, off);
        if (lane == 0) h[j] = fmaxf(s + fc1b[j], 0.0f);
    }
    __syncthreads();

    if (wv < 4) {
        const int k = wv;
        float s = h[lane] * fc2w[k * 128 + lane] + h[lane + 64] * fc2w[k * 128 + lane + 64];
        #pragma unroll
        for (int off = 32; off; off >>= 1) s += __shfl_down(s, off);
        if (lane == 0) att_s[k] = (s + fc2b[k]) * (1.0f / 30.0f);
    }
    __syncthreads();

    if (tid == 0) {
        float l0 = att_s[0], l1 = att_s[1], l2 = att_s[2], l3 = att_s[3];
        float m = fmaxf(fmaxf(l0, l1), fmaxf(l2, l3));
        float e0 = expf(l0 - m), e1 = expf(l1 - m), e2 = expf(l2 - m), e3 = expf(l3 - m);
        float inv = 1.0f / (e0 + e1 + e2 + e3);
        att_s[0] = e0 * inv; att_s[1] = e1 * inv; att_s[2] = e2 * inv; att_s[3] = e3 * inv;
        att_out[b * 4 + 0] = att_s[0]; att_out[b * 4 + 1] = att_s[1];
        att_out[b * 4 + 2] = att_s[2]; att_out[b * 4 + 3] = att_s[3];
    }
    __syncthreads();

    if (tid < 512) {
        bagg_out[b * 512 + tid] = att_s[0] * bias[tid] + att_s[1] * bias[512 + tid]
                                + att_s[2] * bias[1024 + tid] + att_s[3] * bias[1536 + tid];
    }
}

// ---------- kernel 2: w_agg[b][o][i] = sum_k att[b][k]*weight[k][o][i], bf16 ----------
__global__ __launch_bounds__(256) void wagg_kernel(
    const float* __restrict__ weight, const float* __restrict__ att,
    unsigned short* __restrict__ wagg)
{
    __shared__ float a_s[64];
    if (threadIdx.x < 64) a_s[threadIdx.x] = att[threadIdx.x];
    __syncthreads();
    const int p = (blockIdx.x * 256 + threadIdx.x) * 4;
    const float4 w0 = *(const float4*)(weight + p);
    const float4 w1 = *(const float4*)(weight + 262144 + p);
    const float4 w2 = *(const float4*)(weight + 524288 + p);
    const float4 w3 = *(const float4*)(weight + 786432 + p);
    #pragma unroll
    for (int b = 0; b < 16; ++b) {
        const float a0 = a_s[4 * b], a1 = a_s[4 * b + 1], a2 = a_s[4 * b + 2], a3 = a_s[4 * b + 3];
        u16x4 r;
        r[0] = f2bf(a0 * w0.x + a1 * w1.x + a2 * w2.x + a3 * w3.x);
        r[1] = f2bf(a0 * w0.y + a1 * w1.y + a2 * w2.y + a3 * w3.y);
        r[2] = f2bf(a0 * w0.z + a1 * w1.z + a2 * w2.z + a3 * w3.z);
        r[3] = f2bf(a0 * w0.w + a1 * w1.w + a2 * w2.w + a3 * w3.w);
        *(u16x4*)(wagg + (size_t)b * 262144 + p) = r;
    }
}

// ---------- kernel 3: out[l][b][o] = sum_i x[l][b][i]*wagg[b][o][i] + bagg[b][o] ----------
// m97-geometry: BM=128, BN=128, BK=32, 256 threads = 4 waves (2m x 2n), wave 64x64,
// acc 4x4 (64 regs), LDS 33 KB, launch_bounds(256,3) -> 3 blocks/CU, 12 waves/CU.
// Double-buffered; per-iter: issue B glds + x loads early, MFMA, convert+write A, barrier.
__global__ __launch_bounds__(256, 3) void gemm_kernel(
    const float* __restrict__ x, const unsigned short* __restrict__ wagg,
    const float* __restrict__ bagg, float* __restrict__ out)
{
    __shared__ unsigned short As[2][128 * 32];
    __shared__ unsigned short Bs[2][128 * 32];
    __shared__ float bsh[128];

    const int tid = threadIdx.x;
    const int bid = blockIdx.x;
    const int b  = bid >> 7;          // 0..15
    const int lt = (bid >> 2) & 31;   // L tile
    const int nt = bid & 3;           // N tile (fastest: 4 blocks share x tile -> L2/L3)
    const int l0 = lt * 128;
    const int n0 = nt * 128;

    const int lane = tid & 63;
    const int wid  = tid >> 6;        // 0..3
    const int wm   = wid >> 1;        // 0..1
    const int wn   = wid & 1;         // 0..1
    const int fr   = lane & 15;
    const int fq   = lane >> 4;

    const unsigned short* wb = wagg + (size_t)b * (512 * 512) + (size_t)n0 * 512;

    if (tid < 128) bsh[tid] = bagg[b * 512 + n0 + tid];

    f32x4 acc[4][4];
    #pragma unroll
    for (int i = 0; i < 4; ++i)
        #pragma unroll
        for (int j = 0; j < 4; ++j) acc[i][j] = f32x4{0.f, 0.f, 0.f, 0.f};

    // A staging: thread covers chunks {tid, tid+256} of 512 (each 8 floats -> one 16B bf16 chunk)
    const int ar0 = tid >> 2;             // row of chunk0 (0..63)
    const int ar1 = ar0 + 64;             // row of chunk1
    const int ac  = (tid & 3) * 8;        // col start
    const int aswz0 = swz_idx(ar0, tid & 3);
    const int aswz1 = swz_idx(ar1, tid & 3);
    const float* xs0 = x + ((size_t)(l0 + ar0) * 16 + b) * 512 + ac;
    const float* xs1 = x + ((size_t)(l0 + ar1) * 16 + b) * 512 + ac;

    // B staging: slots {tid, tid+256} of 512 -> pre-swizzled global source offsets
    int bofs[2];
    #pragma unroll
    for (int it = 0; it < 2; ++it) {
        const int s = tid + it * 256;
        const int p = s >> 3, q = s & 7;
        const int v = q ^ (p & 7);
        const int row = (p << 1) | (v >> 2);
        const int cch = v & 3;
        bofs[it] = row * 512 + cch * 8;
    }

    // fragment read indices (loop-invariant, swizzled)
    int aidx[4], bidx[4];
    #pragma unroll
    for (int mf = 0; mf < 4; ++mf) aidx[mf] = swz_idx(wm * 64 + mf * 16 + fr, fq);
    #pragma unroll
    for (int nf = 0; nf < 4; ++nf) bidx[nf] = swz_idx(wn * 64 + nf * 16 + fr, fq);

    // --- prologue: stage kt=0 into buffer 0 ---
    {
        const float4 v0 = *(const float4*)(xs0);
        const float4 v1 = *(const float4*)(xs0 + 4);
        const float4 v2 = *(const float4*)(xs1);
        const float4 v3 = *(const float4*)(xs1 + 4);
        u16x8 pk;
        pk[0] = f2bf(v0.x); pk[1] = f2bf(v0.y); pk[2] = f2bf(v0.z); pk[3] = f2bf(v0.w);
        pk[4] = f2bf(v1.x); pk[5] = f2bf(v1.y); pk[6] = f2bf(v1.z); pk[7] = f2bf(v1.w);
        *(u16x8*)&As[0][aswz0] = pk;
        pk[0] = f2bf(v2.x); pk[1] = f2bf(v2.y); pk[2] = f2bf(v2.z); pk[3] = f2bf(v2.w);
        pk[4] = f2bf(v3.x); pk[5] = f2bf(v3.y); pk[6] = f2bf(v3.z); pk[7] = f2bf(v3.w);
        *(u16x8*)&As[0][aswz1] = pk;
        #pragma unroll
        for (int it = 0; it < 2; ++it) {
            char* dst = (char*)&Bs[0][0] + (tid + it * 256) * 16;
            __builtin_amdgcn_global_load_lds(
                (const __attribute__((address_space(1))) void*)(wb + bofs[it]),
                (__attribute__((address_space(3))) void*)dst, 16, 0, 0);
        }
    }
    __syncthreads();

    int cur = 0;
    for (int kt = 0; kt < 16; ++kt) {
        const int nxt = cur ^ 1;
        float4 v0, v1, v2, v3;
        if (kt < 15) {
            const int k0n = (kt + 1) * 32;
            // B glds first
            #pragma unroll
            for (int it = 0; it < 2; ++it) {
                char* dst = (char*)&Bs[nxt][0] + (tid + it * 256) * 16;
                __builtin_amdgcn_global_load_lds(
                    (const __attribute__((address_space(1))) void*)(wb + bofs[it] + k0n),
                    (__attribute__((address_space(3))) void*)dst, 16, 0, 0);
            }
            __builtin_amdgcn_sched_barrier(0);
            // x loads for next tile
            v0 = *(const float4*)(xs0 + k0n);
            v1 = *(const float4*)(xs0 + k0n + 4);
            v2 = *(const float4*)(xs1 + k0n);
            v3 = *(const float4*)(xs1 + k0n + 4);
            __builtin_amdgcn_sched_barrier(0);
        }
        // current tile: fragments + MFMA
        bfx8 af[4], bfr[4];
        #pragma unroll
        for (int mf = 0; mf < 4; ++mf)
            af[mf] = *reinterpret_cast<const bfx8*>(&As[cur][aidx[mf]]);
        #pragma unroll
        for (int nf = 0; nf < 4; ++nf)
            bfr[nf] = *reinterpret_cast<const bfx8*>(&Bs[cur][bidx[nf]]);
        #pragma unroll
        for (int mf = 0; mf < 4; ++mf)
            #pragma unroll
            for (int nf = 0; nf < 4; ++nf)
                acc[mf][nf] = __builtin_amdgcn_mfma_f32_16x16x32_bf16(af[mf], bfr[nf], acc[mf][nf], 0, 0, 0);
        if (kt < 15) {
            u16x8 pk;
            pk[0] = f2bf(v0.x); pk[1] = f2bf(v0.y); pk[2] = f2bf(v0.z); pk[3] = f2bf(v0.w);
            pk[4] = f2bf(v1.x); pk[5] = f2bf(v1.y); pk[6] = f2bf(v1.z); pk[7] = f2bf(v1.w);
            *(u16x8*)&As[nxt][aswz0] = pk;
            pk[0] = f2bf(v2.x); pk[1] = f2bf(v2.y); pk[2] = f2bf(v2.z); pk[3] = f2bf(v2.w);
            pk[4] = f2bf(v3.x); pk[5] = f2bf(v3.y); pk[6] = f2bf(v3.z); pk[7] = f2bf(v3.w);
            *(u16x8*)&As[nxt][aswz1] = pk;
            __syncthreads();
            cur = nxt;
        }
    }

    // --- epilogue: C/D map col=lane&15 (n), row=(lane>>4)*4+r (m) ---
    #pragma unroll
    for (int mf = 0; mf < 4; ++mf) {
        #pragma unroll
        for (int nf = 0; nf < 4; ++nf) {
            const int on = wn * 64 + nf * 16 + fr;
            const float bb = bsh[on];
            const int lrow = l0 + wm * 64 + mf * 16 + fq * 4;
            float* op = out + ((size_t)lrow * 16 + b) * 512 + n0 + on;
            const f32x4 a = acc[mf][nf];
            op[0]        = a[0] + bb;
            op[8192]     = a[1] + bb;
            op[2 * 8192] = a[2] + bb;
            op[3 * 8192] = a[3] + bb;
        }
    }
}

extern "C" void kernel_launch(void* const* d_in, const int* in_sizes, int n_in,
                              void* d_out, int out_size, void* d_ws, size_t ws_size,
                              hipStream_t stream) {
    const float* x      = (const float*)d_in[0];
    const float* cond   = (const float*)d_in[1];
    const float* fc1w   = (const float*)d_in[2];
    const float* fc1b   = (const float*)d_in[3];
    const float* fc2w   = (const float*)d_in[4];
    const float* fc2b   = (const float*)d_in[5];
    const float* weight = (const float*)d_in[6];
    const float* bias   = (const float*)d_in[7];
    float* out = (float*)d_out;

    char* ws = (char*)d_ws;
    float* att_ws  = (float*)ws;                       // 64 f32
    float* bagg_ws = (float*)(ws + 1024);              // 8192 f32
    unsigned short* wagg_ws = (unsigned short*)(ws + 65536);  // 8 MiB bf16

    att_kernel<<<16, 1024, 0, stream>>>(cond, fc1w, fc1b, fc2w, fc2b, bias, att_ws, bagg_ws);
    wagg_kernel<<<256, 256, 0, stream>>>(weight, att_ws, wagg_ws);
    gemm_kernel<<<2048, 256, 0, stream>>>(x, wagg_ws, bagg_ws, out);
}

// Round 8
// 122.167 us; speedup vs baseline: 1.0281x; 1.0281x over previous
//
#include <hip/hip_runtime.h>
#include <hip/hip_bf16.h>

// L=4096, B=16, C_IN=512, C_OUT=512, C_COND=512, K=4, HID=128, T=30
typedef __bf16 bfx8 __attribute__((ext_vector_type(8)));
typedef float f32x4 __attribute__((ext_vector_type(4)));
typedef unsigned short u16x8 __attribute__((ext_vector_type(8)));
typedef unsigned short u16x4 __attribute__((ext_vector_type(4)));

__device__ __forceinline__ unsigned short f2bf(float f) {
    unsigned int u = __builtin_bit_cast(unsigned int, f);
    u += 0x7fffu + ((u >> 16) & 1u);          // RNE
    return (unsigned short)(u >> 16);
}

// XOR swizzle within each 2-row (128 B) unit of a [rows][32] bf16 tile.
__device__ __forceinline__ int swz_idx(int row, int chunk) {
    const int p = row >> 1;
    const int q = (((row & 1) << 2) | chunk) ^ (p & 7);
    return p * 64 + q * 8;
}

// ---------- kernel 1: conditioning MLP. One block per b. ----------
__global__ __launch_bounds__(1024) void att_kernel(
    const float* __restrict__ cond, const float* __restrict__ fc1w,
    const float* __restrict__ fc1b, const float* __restrict__ fc2w,
    const float* __restrict__ fc2b, const float* __restrict__ bias,
    float* __restrict__ att_out, float* __restrict__ bagg_out)
{
    __shared__ float h[128];
    __shared__ float att_s[4];
    const int b    = blockIdx.x;
    const int tid  = threadIdx.x;
    const int lane = tid & 63;
    const int wv   = tid >> 6;          // 0..15

    for (int j = wv; j < 128; j += 16) {
        const float* c = cond + b * 512 + lane * 8;
        const float* w = fc1w + j * 512 + lane * 8;
        const float4 c0 = *(const float4*)c, c1 = *(const float4*)(c + 4);
        const float4 w0 = *(const float4*)w, w1 = *(const float4*)(w + 4);
        float s = c0.x * w0.x + c0.y * w0.y + c0.z * w0.z + c0.w * w0.w
                + c1.x * w1.x + c1.y * w1.y + c1.z * w1.z + c1.w * w1.w;
        #pragma unroll
        for (int off = 32; off; off >>= 1) s += __shfl_down(s, off);
        if (lane == 0) h[j] = fmaxf(s + fc1b[j], 0.0f);
    }
    __syncthreads();

    if (wv < 4) {
        const int k = wv;
        float s = h[lane] * fc2w[k * 128 + lane] + h[lane + 64] * fc2w[k * 128 + lane + 64];
        #pragma unroll
        for (int off = 32; off; off >>= 1) s += __shfl_down(s, off);
        if (lane == 0) att_s[k] = (s + fc2b[k]) * (1.0f / 30.0f);
    }
    __syncthreads();

    if (tid == 0) {
        float l0 = att_s[0], l1 = att_s[1], l2 = att_s[2], l3 = att_s[3];
        float m = fmaxf(fmaxf(l0, l1), fmaxf(l2, l3));
        float e0 = expf(l0 - m), e1 = expf(l1 - m), e2 = expf(l2 - m), e3 = expf(l3 - m);
        float inv = 1.0f / (e0 + e1 + e2 + e3);
        att_s[0] = e0 * inv; att_s[1] = e1 * inv; att_s[2] = e2 * inv; att_s[3] = e3 * inv;
        att_out[b * 4 + 0] = att_s[0]; att_out[b * 4 + 1] = att_s[1];
        att_out[b * 4 + 2] = att_s[2]; att_out[b * 4 + 3] = att_s[3];
    }
    __syncthreads();

    if (tid < 512) {
        bagg_out[b * 512 + tid] = att_s[0] * bias[tid] + att_s[1] * bias[512 + tid]
                                + att_s[2] * bias[1024 + tid] + att_s[3] * bias[1536 + tid];
    }
}

// ---------- kernel 2: w_agg[b][o][i] = sum_k att[b][k]*weight[k][o][i], bf16 ----------
__global__ __launch_bounds__(256) void wagg_kernel(
    const float* __restrict__ weight, const float* __restrict__ att,
    unsigned short* __restrict__ wagg)
{
    __shared__ float a_s[64];
    if (threadIdx.x < 64) a_s[threadIdx.x] = att[threadIdx.x];
    __syncthreads();
    const int p = (blockIdx.x * 256 + threadIdx.x) * 4;
    const float4 w0 = *(const float4*)(weight + p);
    const float4 w1 = *(const float4*)(weight + 262144 + p);
    const float4 w2 = *(const float4*)(weight + 524288 + p);
    const float4 w3 = *(const float4*)(weight + 786432 + p);
    #pragma unroll
    for (int b = 0; b < 16; ++b) {
        const float a0 = a_s[4 * b], a1 = a_s[4 * b + 1], a2 = a_s[4 * b + 2], a3 = a_s[4 * b + 3];
        u16x4 r;
        r[0] = f2bf(a0 * w0.x + a1 * w1.x + a2 * w2.x + a3 * w3.x);
        r[1] = f2bf(a0 * w0.y + a1 * w1.y + a2 * w2.y + a3 * w3.y);
        r[2] = f2bf(a0 * w0.z + a1 * w1.z + a2 * w2.z + a3 * w3.z);
        r[3] = f2bf(a0 * w0.w + a1 * w1.w + a2 * w2.w + a3 * w3.w);
        *(u16x4*)(wagg + (size_t)b * 262144 + p) = r;
    }
}

// ---------- kernel 3: out[l][b][o] = sum_i x[l][b][i]*wagg[b][o][i] + bagg[b][o] ----------
// BM=128, BN=128, BK=32, 256 threads = 4 waves (2m x 2n), wave 64x64, acc 4x4,
// 3 blocks/CU. XCD-chunked bijective swizzle (T1): each XCD owns 256 consecutive
// logical blocks (= 2 b-values); the 4 nt-blocks sharing an x-tile are consecutive
// on the SAME XCD -> x-tile fetched once into that XCD's L2.
__global__ __launch_bounds__(256, 3) void gemm_kernel(
    const float* __restrict__ x, const unsigned short* __restrict__ wagg,
    const float* __restrict__ bagg, float* __restrict__ out)
{
    __shared__ unsigned short As[2][128 * 32];
    __shared__ unsigned short Bs[2][128 * 32];
    __shared__ float bsh[128];

    const int tid = threadIdx.x;
    // --- XCD swizzle: nwg=2048, nxcd=8, cpx=256 (divides evenly -> bijective) ---
    const int bid = (blockIdx.x & 7) * 256 + (blockIdx.x >> 3);
    const int b  = bid >> 7;          // 0..15
    const int lt = (bid >> 2) & 31;   // L tile
    const int nt = bid & 3;           // N tile (fastest: 4 same-XCD blocks share x tile)
    const int l0 = lt * 128;
    const int n0 = nt * 128;

    const int lane = tid & 63;
    const int wid  = tid >> 6;        // 0..3
    const int wm   = wid >> 1;        // 0..1
    const int wn   = wid & 1;         // 0..1
    const int fr   = lane & 15;
    const int fq   = lane >> 4;

    const unsigned short* wb = wagg + (size_t)b * (512 * 512) + (size_t)n0 * 512;

    if (tid < 128) bsh[tid] = bagg[b * 512 + n0 + tid];

    f32x4 acc[4][4];
    #pragma unroll
    for (int i = 0; i < 4; ++i)
        #pragma unroll
        for (int j = 0; j < 4; ++j) acc[i][j] = f32x4{0.f, 0.f, 0.f, 0.f};

    // A staging: thread covers chunks {tid, tid+256} of 512
    const int ar0 = tid >> 2;
    const int ar1 = ar0 + 64;
    const int ac  = (tid & 3) * 8;
    const int aswz0 = swz_idx(ar0, tid & 3);
    const int aswz1 = swz_idx(ar1, tid & 3);
    const float* xs0 = x + ((size_t)(l0 + ar0) * 16 + b) * 512 + ac;
    const float* xs1 = x + ((size_t)(l0 + ar1) * 16 + b) * 512 + ac;

    // B staging: slots {tid, tid+256} -> pre-swizzled global source offsets
    int bofs[2];
    #pragma unroll
    for (int it = 0; it < 2; ++it) {
        const int s = tid + it * 256;
        const int p = s >> 3, q = s & 7;
        const int v = q ^ (p & 7);
        const int row = (p << 1) | (v >> 2);
        const int cch = v & 3;
        bofs[it] = row * 512 + cch * 8;
    }

    int aidx[4], bidx[4];
    #pragma unroll
    for (int mf = 0; mf < 4; ++mf) aidx[mf] = swz_idx(wm * 64 + mf * 16 + fr, fq);
    #pragma unroll
    for (int nf = 0; nf < 4; ++nf) bidx[nf] = swz_idx(wn * 64 + nf * 16 + fr, fq);

    // --- prologue: stage kt=0 into buffer 0 ---
    {
        const float4 v0 = *(const float4*)(xs0);
        const float4 v1 = *(const float4*)(xs0 + 4);
        const float4 v2 = *(const float4*)(xs1);
        const float4 v3 = *(const float4*)(xs1 + 4);
        u16x8 pk;
        pk[0] = f2bf(v0.x); pk[1] = f2bf(v0.y); pk[2] = f2bf(v0.z); pk[3] = f2bf(v0.w);
        pk[4] = f2bf(v1.x); pk[5] = f2bf(v1.y); pk[6] = f2bf(v1.z); pk[7] = f2bf(v1.w);
        *(u16x8*)&As[0][aswz0] = pk;
        pk[0] = f2bf(v2.x); pk[1] = f2bf(v2.y); pk[2] = f2bf(v2.z); pk[3] = f2bf(v2.w);
        pk[4] = f2bf(v3.x); pk[5] = f2bf(v3.y); pk[6] = f2bf(v3.z); pk[7] = f2bf(v3.w);
        *(u16x8*)&As[0][aswz1] = pk;
        #pragma unroll
        for (int it = 0; it < 2; ++it) {
            char* dst = (char*)&Bs[0][0] + (tid + it * 256) * 16;
            __builtin_amdgcn_global_load_lds(
                (const __attribute__((address_space(1))) void*)(wb + bofs[it]),
                (__attribute__((address_space(3))) void*)dst, 16, 0, 0);
        }
    }
    __syncthreads();

    int cur = 0;
    for (int kt = 0; kt < 16; ++kt) {
        const int nxt = cur ^ 1;
        float4 v0, v1, v2, v3;
        if (kt < 15) {
            const int k0n = (kt + 1) * 32;
            #pragma unroll
            for (int it = 0; it < 2; ++it) {
                char* dst = (char*)&Bs[nxt][0] + (tid + it * 256) * 16;
                __builtin_amdgcn_global_load_lds(
                    (const __attribute__((address_space(1))) void*)(wb + bofs[it] + k0n),
                    (__attribute__((address_space(3))) void*)dst, 16, 0, 0);
            }
            __builtin_amdgcn_sched_barrier(0);
            v0 = *(const float4*)(xs0 + k0n);
            v1 = *(const float4*)(xs0 + k0n + 4);
            v2 = *(const float4*)(xs1 + k0n);
            v3 = *(const float4*)(xs1 + k0n + 4);
            __builtin_amdgcn_sched_barrier(0);
        }
        bfx8 af[4], bfr[4];
        #pragma unroll
        for (int mf = 0; mf < 4; ++mf)
            af[mf] = *reinterpret_cast<const bfx8*>(&As[cur][aidx[mf]]);
        #pragma unroll
        for (int nf = 0; nf < 4; ++nf)
            bfr[nf] = *reinterpret_cast<const bfx8*>(&Bs[cur][bidx[nf]]);
        #pragma unroll
        for (int mf = 0; mf < 4; ++mf)
            #pragma unroll
            for (int nf = 0; nf < 4; ++nf)
                acc[mf][nf] = __builtin_amdgcn_mfma_f32_16x16x32_bf16(af[mf], bfr[nf], acc[mf][nf], 0, 0, 0);
        if (kt < 15) {
            u16x8 pk;
            pk[0] = f2bf(v0.x); pk[1] = f2bf(v0.y); pk[2] = f2bf(v0.z); pk[3] = f2bf(v0.w);
            pk[4] = f2bf(v1.x); pk[5] = f2bf(v1.y); pk[6] = f2bf(v1.z); pk[7] = f2bf(v1.w);
            *(u16x8*)&As[nxt][aswz0] = pk;
            pk[0] = f2bf(v2.x); pk[1] = f2bf(v2.y); pk[2] = f2bf(v2.z); pk[3] = f2bf(v2.w);
            pk[4] = f2bf(v3.x); pk[5] = f2bf(v3.y); pk[6] = f2bf(v3.z); pk[7] = f2bf(v3.w);
            *(u16x8*)&As[nxt][aswz1] = pk;
            __syncthreads();
            cur = nxt;
        }
    }

    // --- epilogue: C/D map col=lane&15 (n), row=(lane>>4)*4+r (m) ---
    #pragma unroll
    for (int mf = 0; mf < 4; ++mf) {
        #pragma unroll
        for (int nf = 0; nf < 4; ++nf) {
            const int on = wn * 64 + nf * 16 + fr;
            const float bb = bsh[on];
            const int lrow = l0 + wm * 64 + mf * 16 + fq * 4;
            float* op = out + ((size_t)lrow * 16 + b) * 512 + n0 + on;
            const f32x4 a = acc[mf][nf];
            op[0]        = a[0] + bb;
            op[8192]     = a[1] + bb;
            op[2 * 8192] = a[2] + bb;
            op[3 * 8192] = a[3] + bb;
        }
    }
}

extern "C" void kernel_launch(void* const* d_in, const int* in_sizes, int n_in,
                              void* d_out, int out_size, void* d_ws, size_t ws_size,
                              hipStream_t stream) {
    const float* x      = (const float*)d_in[0];
    const float* cond   = (const float*)d_in[1];
    const float* fc1w   = (const float*)d_in[2];
    const float* fc1b   = (const float*)d_in[3];
    const float* fc2w   = (const float*)d_in[4];
    const float* fc2b   = (const float*)d_in[5];
    const float* weight = (const float*)d_in[6];
    const float* bias   = (const float*)d_in[7];
    float* out = (float*)d_out;

    char* ws = (char*)d_ws;
    float* att_ws  = (float*)ws;                       // 64 f32
    float* bagg_ws = (float*)(ws + 1024);              // 8192 f32
    unsigned short* wagg_ws = (unsigned short*)(ws + 65536);  // 8 MiB bf16

    att_kernel<<<16, 1024, 0, stream>>>(cond, fc1w, fc1b, fc2w, fc2b, bias, att_ws, bagg_ws);
    wagg_kernel<<<256, 256, 0, stream>>>(weight, att_ws, wagg_ws);
    gemm_kernel<<<2048, 256, 0, stream>>>(x, wagg_ws, bagg_ws, out);
}

// Round 9
// 114.681 us; speedup vs baseline: 1.0952x; 1.0653x over previous
//
#include <hip/hip_runtime.h>
#include <hip/hip_bf16.h>

// L=4096, B=16, C_IN=512, C_OUT=512, C_COND=512, K=4, HID=128, T=30
typedef __bf16 bfx8 __attribute__((ext_vector_type(8)));
typedef float f32x4 __attribute__((ext_vector_type(4)));
typedef unsigned short u16x8 __attribute__((ext_vector_type(8)));
typedef unsigned short u16x4 __attribute__((ext_vector_type(4)));

__device__ __forceinline__ unsigned short f2bf(float f) {
    unsigned int u = __builtin_bit_cast(unsigned int, f);
    u += 0x7fffu + ((u >> 16) & 1u);          // RNE
    return (unsigned short)(u >> 16);
}

// XOR swizzle within each 2-row (128 B) unit of a [rows][32] bf16 tile.
__device__ __forceinline__ int swz_idx(int row, int chunk) {
    const int p = row >> 1;
    const int q = (((row & 1) << 2) | chunk) ^ (p & 7);
    return p * 64 + q * 8;
}

// ---------- kernel 1: conditioning MLP. One block per b. ----------
__global__ __launch_bounds__(1024) void att_kernel(
    const float* __restrict__ cond, const float* __restrict__ fc1w,
    const float* __restrict__ fc1b, const float* __restrict__ fc2w,
    const float* __restrict__ fc2b, const float* __restrict__ bias,
    float* __restrict__ att_out, float* __restrict__ bagg_out)
{
    __shared__ float h[128];
    __shared__ float att_s[4];
    const int b    = blockIdx.x;
    const int tid  = threadIdx.x;
    const int lane = tid & 63;
    const int wv   = tid >> 6;          // 0..15

    for (int j = wv; j < 128; j += 16) {
        const float* c = cond + b * 512 + lane * 8;
        const float* w = fc1w + j * 512 + lane * 8;
        const float4 c0 = *(const float4*)c, c1 = *(const float4*)(c + 4);
        const float4 w0 = *(const float4*)w, w1 = *(const float4*)(w + 4);
        float s = c0.x * w0.x + c0.y * w0.y + c0.z * w0.z + c0.w * w0.w
                + c1.x * w1.x + c1.y * w1.y + c1.z * w1.z + c1.w * w1.w;
        #pragma unroll
        for (int off = 32; off; off >>= 1) s += __shfl_down(s, off);
        if (lane == 0) h[j] = fmaxf(s + fc1b[j], 0.0f);
    }
    __syncthreads();

    if (wv < 4) {
        const int k = wv;
        float s = h[lane] * fc2w[k * 128 + lane] + h[lane + 64] * fc2w[k * 128 + lane + 64];
        #pragma unroll
        for (int off = 32; off; off >>= 1) s += __shfl_down(s, off);
        if (lane == 0) att_s[k] = (s + fc2b[k]) * (1.0f / 30.0f);
    }
    __syncthreads();

    if (tid == 0) {
        float l0 = att_s[0], l1 = att_s[1], l2 = att_s[2], l3 = att_s[3];
        float m = fmaxf(fmaxf(l0, l1), fmaxf(l2, l3));
        float e0 = expf(l0 - m), e1 = expf(l1 - m), e2 = expf(l2 - m), e3 = expf(l3 - m);
        float inv = 1.0f / (e0 + e1 + e2 + e3);
        att_s[0] = e0 * inv; att_s[1] = e1 * inv; att_s[2] = e2 * inv; att_s[3] = e3 * inv;
        att_out[b * 4 + 0] = att_s[0]; att_out[b * 4 + 1] = att_s[1];
        att_out[b * 4 + 2] = att_s[2]; att_out[b * 4 + 3] = att_s[3];
    }
    __syncthreads();

    if (tid < 512) {
        bagg_out[b * 512 + tid] = att_s[0] * bias[tid] + att_s[1] * bias[512 + tid]
                                + att_s[2] * bias[1024 + tid] + att_s[3] * bias[1536 + tid];
    }
}

// ---------- kernel 2: w_agg[b][o][i] = sum_k att[b][k]*weight[k][o][i], bf16 ----------
__global__ __launch_bounds__(256) void wagg_kernel(
    const float* __restrict__ weight, const float* __restrict__ att,
    unsigned short* __restrict__ wagg)
{
    __shared__ float a_s[64];
    if (threadIdx.x < 64) a_s[threadIdx.x] = att[threadIdx.x];
    __syncthreads();
    const int p = (blockIdx.x * 256 + threadIdx.x) * 4;
    const float4 w0 = *(const float4*)(weight + p);
    const float4 w1 = *(const float4*)(weight + 262144 + p);
    const float4 w2 = *(const float4*)(weight + 524288 + p);
    const float4 w3 = *(const float4*)(weight + 786432 + p);
    #pragma unroll
    for (int b = 0; b < 16; ++b) {
        const float a0 = a_s[4 * b], a1 = a_s[4 * b + 1], a2 = a_s[4 * b + 2], a3 = a_s[4 * b + 3];
        u16x4 r;
        r[0] = f2bf(a0 * w0.x + a1 * w1.x + a2 * w2.x + a3 * w3.x);
        r[1] = f2bf(a0 * w0.y + a1 * w1.y + a2 * w2.y + a3 * w3.y);
        r[2] = f2bf(a0 * w0.z + a1 * w1.z + a2 * w2.z + a3 * w3.z);
        r[3] = f2bf(a0 * w0.w + a1 * w1.w + a2 * w2.w + a3 * w3.w);
        *(u16x4*)(wagg + (size_t)b * 262144 + p) = r;
    }
}

// ---------- kernel 3: out[l][b][o] = sum_i x[l][b][i]*wagg[b][o][i] + bagg[b][o] ----------
// BM=128, BN=128, BK=32, 4 waves (2x2), acc 4x4, 3 blocks/CU, XCD-chunked swizzle.
// T4+T14: x prefetched 2 K-steps deep; per-iter barrier is counted vmcnt(4)
// (B-glds done, 4 x-loads stay in flight) -- never drain to 0 in the main loop.
__global__ __launch_bounds__(256, 3) void gemm_kernel(
    const float* __restrict__ x, const unsigned short* __restrict__ wagg,
    const float* __restrict__ bagg, float* __restrict__ out)
{
    __shared__ unsigned short As[2][128 * 32];
    __shared__ unsigned short Bs[2][128 * 32];
    __shared__ float bsh[128];

    const int tid = threadIdx.x;
    // XCD swizzle: nwg=2048, nxcd=8, cpx=256 (bijective)
    const int bid = (blockIdx.x & 7) * 256 + (blockIdx.x >> 3);
    const int b  = bid >> 7;          // 0..15
    const int lt = (bid >> 2) & 31;   // L tile
    const int nt = bid & 3;           // N tile (4 same-XCD blocks share x tile)
    const int l0 = lt * 128;
    const int n0 = nt * 128;

    const int lane = tid & 63;
    const int wid  = tid >> 6;
    const int wm   = wid >> 1;
    const int wn   = wid & 1;
    const int fr   = lane & 15;
    const int fq   = lane >> 4;

    const unsigned short* wb = wagg + (size_t)b * (512 * 512) + (size_t)n0 * 512;

    if (tid < 128) bsh[tid] = bagg[b * 512 + n0 + tid];

    f32x4 acc[4][4];
    #pragma unroll
    for (int i = 0; i < 4; ++i)
        #pragma unroll
        for (int j = 0; j < 4; ++j) acc[i][j] = f32x4{0.f, 0.f, 0.f, 0.f};

    // A staging: thread covers chunks {tid, tid+256} of 512
    const int ar0 = tid >> 2;
    const int ar1 = ar0 + 64;
    const int ac  = (tid & 3) * 8;
    const int aswz0 = swz_idx(ar0, tid & 3);
    const int aswz1 = swz_idx(ar1, tid & 3);
    const float* xs0 = x + ((size_t)(l0 + ar0) * 16 + b) * 512 + ac;
    const float* xs1 = x + ((size_t)(l0 + ar1) * 16 + b) * 512 + ac;

    // B staging: slots {tid, tid+256} -> pre-swizzled global source offsets
    int bofs[2];
    #pragma unroll
    for (int it = 0; it < 2; ++it) {
        const int s = tid + it * 256;
        const int p = s >> 3, q = s & 7;
        const int v = q ^ (p & 7);
        const int row = (p << 1) | (v >> 2);
        const int cch = v & 3;
        bofs[it] = row * 512 + cch * 8;
    }

    int aidx[4], bidx[4];
    #pragma unroll
    for (int mf = 0; mf < 4; ++mf) aidx[mf] = swz_idx(wm * 64 + mf * 16 + fr, fq);
    #pragma unroll
    for (int nf = 0; nf < 4; ++nf) bidx[nf] = swz_idx(wn * 64 + nf * 16 + fr, fq);

    // --- prologue: stage kt=0 (A from x(0), B glds), issue x(1) loads ---
    float4 xv0, xv1, xv2, xv3;   // x values for tile kt+1 (to be written next iter)
    {
        const float4 v0 = *(const float4*)(xs0);
        const float4 v1 = *(const float4*)(xs0 + 4);
        const float4 v2 = *(const float4*)(xs1);
        const float4 v3 = *(const float4*)(xs1 + 4);
        u16x8 pk;
        pk[0] = f2bf(v0.x); pk[1] = f2bf(v0.y); pk[2] = f2bf(v0.z); pk[3] = f2bf(v0.w);
        pk[4] = f2bf(v1.x); pk[5] = f2bf(v1.y); pk[6] = f2bf(v1.z); pk[7] = f2bf(v1.w);
        *(u16x8*)&As[0][aswz0] = pk;
        pk[0] = f2bf(v2.x); pk[1] = f2bf(v2.y); pk[2] = f2bf(v2.z); pk[3] = f2bf(v2.w);
        pk[4] = f2bf(v3.x); pk[5] = f2bf(v3.y); pk[6] = f2bf(v3.z); pk[7] = f2bf(v3.w);
        *(u16x8*)&As[0][aswz1] = pk;
        #pragma unroll
        for (int it = 0; it < 2; ++it) {
            char* dst = (char*)&Bs[0][0] + (tid + it * 256) * 16;
            __builtin_amdgcn_global_load_lds(
                (const __attribute__((address_space(1))) void*)(wb + bofs[it]),
                (__attribute__((address_space(3))) void*)dst, 16, 0, 0);
        }
        // x(1) prefetch (stays in flight across the barrier)
        xv0 = *(const float4*)(xs0 + 32);
        xv1 = *(const float4*)(xs0 + 36);
        xv2 = *(const float4*)(xs1 + 32);
        xv3 = *(const float4*)(xs1 + 36);
    }
    // B-glds (oldest 2) must be done; 4 x-loads may remain in flight
    asm volatile("s_waitcnt vmcnt(4) lgkmcnt(0)" ::: "memory");
    __builtin_amdgcn_s_barrier();

    int cur = 0;
    for (int kt = 0; kt < 16; ++kt) {
        const int nxt = cur ^ 1;
        float4 xn0, xn1, xn2, xn3;
        if (kt < 15) {
            const int k0n = (kt + 1) * 32;
            // B glds FIRST (oldest at the barrier -> covered by vmcnt(4))
            #pragma unroll
            for (int it = 0; it < 2; ++it) {
                char* dst = (char*)&Bs[nxt][0] + (tid + it * 256) * 16;
                __builtin_amdgcn_global_load_lds(
                    (const __attribute__((address_space(1))) void*)(wb + bofs[it] + k0n),
                    (__attribute__((address_space(3))) void*)dst, 16, 0, 0);
            }
            __builtin_amdgcn_sched_barrier(0);
            // x(kt+2) issue SECOND (stays in flight across barrier), clamped tail
            const int kp = (kt + 2 <= 15) ? (kt + 2) * 32 : 15 * 32;
            xn0 = *(const float4*)(xs0 + kp);
            xn1 = *(const float4*)(xs0 + kp + 4);
            xn2 = *(const float4*)(xs1 + kp);
            xn3 = *(const float4*)(xs1 + kp + 4);
            __builtin_amdgcn_sched_barrier(0);
        }
        // current tile: fragments + MFMA
        bfx8 af[4], bfr[4];
        #pragma unroll
        for (int mf = 0; mf < 4; ++mf)
            af[mf] = *reinterpret_cast<const bfx8*>(&As[cur][aidx[mf]]);
        #pragma unroll
        for (int nf = 0; nf < 4; ++nf)
            bfr[nf] = *reinterpret_cast<const bfx8*>(&Bs[cur][bidx[nf]]);
        #pragma unroll
        for (int mf = 0; mf < 4; ++mf)
            #pragma unroll
            for (int nf = 0; nf < 4; ++nf)
                acc[mf][nf] = __builtin_amdgcn_mfma_f32_16x16x32_bf16(af[mf], bfr[nf], acc[mf][nf], 0, 0, 0);
        if (kt < 15) {
            // write A tile for kt+1 from regs loaded at kt-1 (latency long gone)
            u16x8 pk;
            pk[0] = f2bf(xv0.x); pk[1] = f2bf(xv0.y); pk[2] = f2bf(xv0.z); pk[3] = f2bf(xv0.w);
            pk[4] = f2bf(xv1.x); pk[5] = f2bf(xv1.y); pk[6] = f2bf(xv1.z); pk[7] = f2bf(xv1.w);
            *(u16x8*)&As[nxt][aswz0] = pk;
            pk[0] = f2bf(xv2.x); pk[1] = f2bf(xv2.y); pk[2] = f2bf(xv2.z); pk[3] = f2bf(xv2.w);
            pk[4] = f2bf(xv3.x); pk[5] = f2bf(xv3.y); pk[6] = f2bf(xv3.z); pk[7] = f2bf(xv3.w);
            *(u16x8*)&As[nxt][aswz1] = pk;
            // counted barrier: B-glds for nxt done; x(kt+2) stays in flight
            asm volatile("s_waitcnt vmcnt(4) lgkmcnt(0)" ::: "memory");
            __builtin_amdgcn_s_barrier();
            cur = nxt;
            xv0 = xn0; xv1 = xn1; xv2 = xn2; xv3 = xn3;
        }
    }

    // --- epilogue: C/D map col=lane&15 (n), row=(lane>>4)*4+r (m) ---
    #pragma unroll
    for (int mf = 0; mf < 4; ++mf) {
        #pragma unroll
        for (int nf = 0; nf < 4; ++nf) {
            const int on = wn * 64 + nf * 16 + fr;
            const float bb = bsh[on];
            const int lrow = l0 + wm * 64 + mf * 16 + fq * 4;
            float* op = out + ((size_t)lrow * 16 + b) * 512 + n0 + on;
            const f32x4 a = acc[mf][nf];
            op[0]        = a[0] + bb;
            op[8192]     = a[1] + bb;
            op[2 * 8192] = a[2] + bb;
            op[3 * 8192] = a[3] + bb;
        }
    }
}

extern "C" void kernel_launch(void* const* d_in, const int* in_sizes, int n_in,
                              void* d_out, int out_size, void* d_ws, size_t ws_size,
                              hipStream_t stream) {
    const float* x      = (const float*)d_in[0];
    const float* cond   = (const float*)d_in[1];
    const float* fc1w   = (const float*)d_in[2];
    const float* fc1b   = (const float*)d_in[3];
    const float* fc2w   = (const float*)d_in[4];
    const float* fc2b   = (const float*)d_in[5];
    const float* weight = (const float*)d_in[6];
    const float* bias   = (const float*)d_in[7];
    float* out = (float*)d_out;

    char* ws = (char*)d_ws;
    float* att_ws  = (float*)ws;                       // 64 f32
    float* bagg_ws = (float*)(ws + 1024);              // 8192 f32
    unsigned short* wagg_ws = (unsigned short*)(ws + 65536);  // 8 MiB bf16

    att_kernel<<<16, 1024, 0, stream>>>(cond, fc1w, fc1b, fc2w, fc2b, bias, att_ws, bagg_ws);
    wagg_kernel<<<256, 256, 0, stream>>>(weight, att_ws, wagg_ws);
    gemm_kernel<<<2048, 256, 0, stream>>>(x, wagg_ws, bagg_ws, out);
}

// Round 10
// 103.726 us; speedup vs baseline: 1.2109x; 1.1056x over previous
//
#include <hip/hip_runtime.h>
#include <hip/hip_bf16.h>

// L=4096, B=16, C_IN=512, C_OUT=512, C_COND=512, K=4, HID=128, T=30
typedef __bf16 bfx8 __attribute__((ext_vector_type(8)));
typedef float f32x4 __attribute__((ext_vector_type(4)));
typedef unsigned short u16x8 __attribute__((ext_vector_type(8)));
typedef unsigned short u16x4 __attribute__((ext_vector_type(4)));

__device__ __forceinline__ unsigned short f2bf(float f) {
    unsigned int u = __builtin_bit_cast(unsigned int, f);
    u += 0x7fffu + ((u >> 16) & 1u);          // RNE
    return (unsigned short)(u >> 16);
}

// XOR swizzle within each 2-row (128 B) unit of a [rows][32] bf16 tile.
__device__ __forceinline__ int swz_idx(int row, int chunk) {
    const int p = row >> 1;
    const int q = (((row & 1) << 2) | chunk) ^ (p & 7);
    return p * 64 + q * 8;
}

// ---------- kernel 1: conditioning MLP. One block per b. ----------
__global__ __launch_bounds__(1024) void att_kernel(
    const float* __restrict__ cond, const float* __restrict__ fc1w,
    const float* __restrict__ fc1b, const float* __restrict__ fc2w,
    const float* __restrict__ fc2b, const float* __restrict__ bias,
    float* __restrict__ att_out, float* __restrict__ bagg_out)
{
    __shared__ float h[128];
    __shared__ float att_s[4];
    const int b    = blockIdx.x;
    const int tid  = threadIdx.x;
    const int lane = tid & 63;
    const int wv   = tid >> 6;          // 0..15

    for (int j = wv; j < 128; j += 16) {
        const float* c = cond + b * 512 + lane * 8;
        const float* w = fc1w + j * 512 + lane * 8;
        const float4 c0 = *(const float4*)c, c1 = *(const float4*)(c + 4);
        const float4 w0 = *(const float4*)w, w1 = *(const float4*)(w + 4);
        float s = c0.x * w0.x + c0.y * w0.y + c0.z * w0.z + c0.w * w0.w
                + c1.x * w1.x + c1.y * w1.y + c1.z * w1.z + c1.w * w1.w;
        #pragma unroll
        for (int off = 32; off; off >>= 1) s += __shfl_down(s, off);
        if (lane == 0) h[j] = fmaxf(s + fc1b[j], 0.0f);
    }
    __syncthreads();

    if (wv < 4) {
        const int k = wv;
        float s = h[lane] * fc2w[k * 128 + lane] + h[lane + 64] * fc2w[k * 128 + lane + 64];
        #pragma unroll
        for (int off = 32; off; off >>= 1) s += __shfl_down(s, off);
        if (lane == 0) att_s[k] = (s + fc2b[k]) * (1.0f / 30.0f);
    }
    __syncthreads();

    if (tid == 0) {
        float l0 = att_s[0], l1 = att_s[1], l2 = att_s[2], l3 = att_s[3];
        float m = fmaxf(fmaxf(l0, l1), fmaxf(l2, l3));
        float e0 = expf(l0 - m), e1 = expf(l1 - m), e2 = expf(l2 - m), e3 = expf(l3 - m);
        float inv = 1.0f / (e0 + e1 + e2 + e3);
        att_s[0] = e0 * inv; att_s[1] = e1 * inv; att_s[2] = e2 * inv; att_s[3] = e3 * inv;
        att_out[b * 4 + 0] = att_s[0]; att_out[b * 4 + 1] = att_s[1];
        att_out[b * 4 + 2] = att_s[2]; att_out[b * 4 + 3] = att_s[3];
    }
    __syncthreads();

    if (tid < 512) {
        bagg_out[b * 512 + tid] = att_s[0] * bias[tid] + att_s[1] * bias[512 + tid]
                                + att_s[2] * bias[1024 + tid] + att_s[3] * bias[1536 + tid];
    }
}

// ---------- kernel 2: w_agg[b][o][i] = sum_k att[b][k]*weight[k][o][i], bf16 ----------
__global__ __launch_bounds__(256) void wagg_kernel(
    const float* __restrict__ weight, const float* __restrict__ att,
    unsigned short* __restrict__ wagg)
{
    __shared__ float a_s[64];
    if (threadIdx.x < 64) a_s[threadIdx.x] = att[threadIdx.x];
    __syncthreads();
    const int p = (blockIdx.x * 256 + threadIdx.x) * 4;
    const float4 w0 = *(const float4*)(weight + p);
    const float4 w1 = *(const float4*)(weight + 262144 + p);
    const float4 w2 = *(const float4*)(weight + 524288 + p);
    const float4 w3 = *(const float4*)(weight + 786432 + p);
    #pragma unroll
    for (int b = 0; b < 16; ++b) {
        const float a0 = a_s[4 * b], a1 = a_s[4 * b + 1], a2 = a_s[4 * b + 2], a3 = a_s[4 * b + 3];
        u16x4 r;
        r[0] = f2bf(a0 * w0.x + a1 * w1.x + a2 * w2.x + a3 * w3.x);
        r[1] = f2bf(a0 * w0.y + a1 * w1.y + a2 * w2.y + a3 * w3.y);
        r[2] = f2bf(a0 * w0.z + a1 * w1.z + a2 * w2.z + a3 * w3.z);
        r[3] = f2bf(a0 * w0.w + a1 * w1.w + a2 * w2.w + a3 * w3.w);
        *(u16x4*)(wagg + (size_t)b * 262144 + p) = r;
    }
}

// ---------- kernel 3: out[l][b][o] = sum_i x[l][b][i]*wagg[b][o][i] + bagg[b][o] ----------
// BM=256, BN=256, BK=32. 512 threads = 8 waves (2m x 4n), wave tile 128x64,
// acc 8x4 (128 AGPR). LDS 65 KB -> 2 blocks/CU. 12 LDS reads per 32 MFMA/wave/step
// (vs 10 per 16 before) -- the LDS:MFMA ratio is the R9 bottleneck fix.
// XCD-chunked swizzle (512 blocks, 64/XCD = 2 b-values). Counted vmcnt(4) barrier,
// x prefetched 2 K-steps deep.
__global__ __launch_bounds__(512, 2) void gemm_kernel(
    const float* __restrict__ x, const unsigned short* __restrict__ wagg,
    const float* __restrict__ bagg, float* __restrict__ out)
{
    __shared__ unsigned short As[2][256 * 32];
    __shared__ unsigned short Bs[2][256 * 32];
    __shared__ float bsh[256];

    const int tid = threadIdx.x;
    // XCD swizzle: nwg=512, nxcd=8, cpx=64 (bijective)
    const int bid = (blockIdx.x & 7) * 64 + (blockIdx.x >> 3);
    const int b  = bid >> 5;          // 0..15
    const int lt = (bid >> 1) & 15;   // L tile (256 rows)
    const int nt = bid & 1;           // N tile (2 same-XCD blocks share x tile)
    const int l0 = lt * 256;
    const int n0 = nt * 256;

    const int lane = tid & 63;
    const int wid  = tid >> 6;        // 0..7
    const int wm   = wid >> 2;        // 0..1
    const int wn   = wid & 3;         // 0..3
    const int fr   = lane & 15;
    const int fq   = lane >> 4;

    const unsigned short* wb = wagg + (size_t)b * (512 * 512) + (size_t)n0 * 512;

    if (tid < 256) bsh[tid] = bagg[b * 512 + n0 + tid];

    f32x4 acc[8][4];
    #pragma unroll
    for (int i = 0; i < 8; ++i)
        #pragma unroll
        for (int j = 0; j < 4; ++j) acc[i][j] = f32x4{0.f, 0.f, 0.f, 0.f};

    // A staging: thread covers 16 consecutive floats: row = tid>>1, col (tid&1)*16
    const int arow = tid >> 1;              // 0..255
    const int acb  = (tid & 1) * 2;         // chunk base
    const int aswz0 = swz_idx(arow, acb);
    const int aswz1 = swz_idx(arow, acb + 1);
    const float* xsrc = x + ((size_t)(l0 + arow) * 16 + b) * 512 + (tid & 1) * 16;

    // B staging: slots {tid, tid+512} of 1024 -> pre-swizzled global source offsets
    int bofs[2];
    #pragma unroll
    for (int it = 0; it < 2; ++it) {
        const int s = tid + it * 512;
        const int p = s >> 3, q = s & 7;
        const int v = q ^ (p & 7);
        const int row = (p << 1) | (v >> 2);
        const int cch = v & 3;
        bofs[it] = row * 512 + cch * 8;
    }

    int aidx[8], bidx[4];
    #pragma unroll
    for (int mf = 0; mf < 8; ++mf) aidx[mf] = swz_idx(wm * 128 + mf * 16 + fr, fq);
    #pragma unroll
    for (int nf = 0; nf < 4; ++nf) bidx[nf] = swz_idx(wn * 64 + nf * 16 + fr, fq);

    // --- prologue: stage kt=0 (A direct, B glds), issue x(1) loads ---
    float4 xv0, xv1, xv2, xv3;   // x data for tile kt+1
    {
        const float4 v0 = *(const float4*)(xsrc);
        const float4 v1 = *(const float4*)(xsrc + 4);
        const float4 v2 = *(const float4*)(xsrc + 8);
        const float4 v3 = *(const float4*)(xsrc + 12);
        u16x8 pk;
        pk[0] = f2bf(v0.x); pk[1] = f2bf(v0.y); pk[2] = f2bf(v0.z); pk[3] = f2bf(v0.w);
        pk[4] = f2bf(v1.x); pk[5] = f2bf(v1.y); pk[6] = f2bf(v1.z); pk[7] = f2bf(v1.w);
        *(u16x8*)&As[0][aswz0] = pk;
        pk[0] = f2bf(v2.x); pk[1] = f2bf(v2.y); pk[2] = f2bf(v2.z); pk[3] = f2bf(v2.w);
        pk[4] = f2bf(v3.x); pk[5] = f2bf(v3.y); pk[6] = f2bf(v3.z); pk[7] = f2bf(v3.w);
        *(u16x8*)&As[0][aswz1] = pk;
        #pragma unroll
        for (int it = 0; it < 2; ++it) {
            char* dst = (char*)&Bs[0][0] + (tid + it * 512) * 16;
            __builtin_amdgcn_global_load_lds(
                (const __attribute__((address_space(1))) void*)(wb + bofs[it]),
                (__attribute__((address_space(3))) void*)dst, 16, 0, 0);
        }
        xv0 = *(const float4*)(xsrc + 32);
        xv1 = *(const float4*)(xsrc + 36);
        xv2 = *(const float4*)(xsrc + 40);
        xv3 = *(const float4*)(xsrc + 44);
    }
    asm volatile("s_waitcnt vmcnt(4) lgkmcnt(0)" ::: "memory");
    __builtin_amdgcn_s_barrier();

    int cur = 0;
    for (int kt = 0; kt < 16; ++kt) {
        const int nxt = cur ^ 1;
        float4 xn0, xn1, xn2, xn3;
        if (kt < 15) {
            const int k0n = (kt + 1) * 32;
            // B glds FIRST (oldest at the barrier -> covered by vmcnt(4))
            #pragma unroll
            for (int it = 0; it < 2; ++it) {
                char* dst = (char*)&Bs[nxt][0] + (tid + it * 512) * 16;
                __builtin_amdgcn_global_load_lds(
                    (const __attribute__((address_space(1))) void*)(wb + bofs[it] + k0n),
                    (__attribute__((address_space(3))) void*)dst, 16, 0, 0);
            }
            __builtin_amdgcn_sched_barrier(0);
            // x(kt+2) issue SECOND (stays in flight across barrier), clamped tail
            const int kp = (kt + 2 <= 15) ? (kt + 2) * 32 : 15 * 32;
            xn0 = *(const float4*)(xsrc + kp);
            xn1 = *(const float4*)(xsrc + kp + 4);
            xn2 = *(const float4*)(xsrc + kp + 8);
            xn3 = *(const float4*)(xsrc + kp + 12);
            __builtin_amdgcn_sched_barrier(0);
        }
        // current tile: B fragments up front, A fragment per mf (limits liveness)
        bfx8 bfr[4];
        #pragma unroll
        for (int nf = 0; nf < 4; ++nf)
            bfr[nf] = *reinterpret_cast<const bfx8*>(&Bs[cur][bidx[nf]]);
        #pragma unroll
        for (int mf = 0; mf < 8; ++mf) {
            const bfx8 af = *reinterpret_cast<const bfx8*>(&As[cur][aidx[mf]]);
            #pragma unroll
            for (int nf = 0; nf < 4; ++nf)
                acc[mf][nf] = __builtin_amdgcn_mfma_f32_16x16x32_bf16(af, bfr[nf], acc[mf][nf], 0, 0, 0);
        }
        if (kt < 15) {
            // write A tile for kt+1 from regs loaded at kt-1 (latency long covered)
            u16x8 pk;
            pk[0] = f2bf(xv0.x); pk[1] = f2bf(xv0.y); pk[2] = f2bf(xv0.z); pk[3] = f2bf(xv0.w);
            pk[4] = f2bf(xv1.x); pk[5] = f2bf(xv1.y); pk[6] = f2bf(xv1.z); pk[7] = f2bf(xv1.w);
            *(u16x8*)&As[nxt][aswz0] = pk;
            pk[0] = f2bf(xv2.x); pk[1] = f2bf(xv2.y); pk[2] = f2bf(xv2.z); pk[3] = f2bf(xv2.w);
            pk[4] = f2bf(xv3.x); pk[5] = f2bf(xv3.y); pk[6] = f2bf(xv3.z); pk[7] = f2bf(xv3.w);
            *(u16x8*)&As[nxt][aswz1] = pk;
            // counted barrier: B-glds for nxt done; x(kt+2) stays in flight
            asm volatile("s_waitcnt vmcnt(4) lgkmcnt(0)" ::: "memory");
            __builtin_amdgcn_s_barrier();
            cur = nxt;
            xv0 = xn0; xv1 = xn1; xv2 = xn2; xv3 = xn3;
        }
    }

    // --- epilogue: C/D map col=lane&15 (n), row=(lane>>4)*4+r (m) ---
    #pragma unroll
    for (int mf = 0; mf < 8; ++mf) {
        #pragma unroll
        for (int nf = 0; nf < 4; ++nf) {
            const int on = wn * 64 + nf * 16 + fr;
            const float bb = bsh[on];
            const int lrow = l0 + wm * 128 + mf * 16 + fq * 4;
            float* op = out + ((size_t)lrow * 16 + b) * 512 + n0 + on;
            const f32x4 a = acc[mf][nf];
            op[0]        = a[0] + bb;
            op[8192]     = a[1] + bb;
            op[2 * 8192] = a[2] + bb;
            op[3 * 8192] = a[3] + bb;
        }
    }
}

extern "C" void kernel_launch(void* const* d_in, const int* in_sizes, int n_in,
                              void* d_out, int out_size, void* d_ws, size_t ws_size,
                              hipStream_t stream) {
    const float* x      = (const float*)d_in[0];
    const float* cond   = (const float*)d_in[1];
    const float* fc1w   = (const float*)d_in[2];
    const float* fc1b   = (const float*)d_in[3];
    const float* fc2w   = (const float*)d_in[4];
    const float* fc2b   = (const float*)d_in[5];
    const float* weight = (const float*)d_in[6];
    const float* bias   = (const float*)d_in[7];
    float* out = (float*)d_out;

    char* ws = (char*)d_ws;
    float* att_ws  = (float*)ws;                       // 64 f32
    float* bagg_ws = (float*)(ws + 1024);              // 8192 f32
    unsigned short* wagg_ws = (unsigned short*)(ws + 65536);  // 8 MiB bf16

    att_kernel<<<16, 1024, 0, stream>>>(cond, fc1w, fc1b, fc2w, fc2b, bias, att_ws, bagg_ws);
    wagg_kernel<<<256, 256, 0, stream>>>(weight, att_ws, wagg_ws);
    gemm_kernel<<<512, 512, 0, stream>>>(x, wagg_ws, bagg_ws, out);
}